// Round 11
// baseline (2509.877 us; speedup 1.0000x reference)
//
#include <hip/hip_runtime.h>

// ---------------- problem constants ----------------
constexpr int N_ = 1024;   // ITEM_SIZE
constexpr int B_ = 64;     // BATCH
constexpr int T_ = 64;     // SEQ
constexpr int CAP = 96;    // cidx capacity per node (max in-degree ~61 incl self-loop)
constexpr int CAPD = 64;   // dst capacity per step (ndst = indeg(item) <= ~61)
constexpr size_t OUT0 = (size_t)B_ * T_ * N_;   // outs f32, then h [B][N][32] f32

// ROUND-24: single-token fix of R23. R23's 16-sub variant used __launch_bounds__(256,4),
// which pushed the allocator to the 64-VGPR occupancy step -> spill (VGPR=64, FETCH
// 7.2GB=112MB/step scratch). The body needs ~112 VGPR; at 112, FOUR waves/SIMD fit in
// hardware anyway (4x112=448<=512), so WPE=2 (the R19-proven bound, VGPR 112) gives the
// 16-sub shape its 4 blocks/CU co-residency from actual usage with NO spill.
// R23 also proved: ws_size >= 18MB (16-sub selected) and 4-blocks/CU co-residency is
// safe (occupancy 47%, passed). This is the clean TLP experiment R16/R23 poisoned.
// Tripwire: VGPR must be ~112. 64 or 128 with GB-scale FETCH = poisoned, not null.

// ---------------- workspace layout (float offsets; Pbuf LAST, variant-sized) ----------------
constexpr size_t WINTo  = 0;        // w_in^T  [j][i] 128*64 = 8192
constexpr size_t WOUTTo = 8192;     // w_out^T                 8192
constexpr size_t WIHTo  = 16384;    // w_ih^T  [j][g]  64*96 = 6144
constexpr size_t WHHo   = 22528;    // w_hh row-major          3072
constexpr size_t WFCo   = 25600;    // 32
constexpr size_t BINo   = 25632;    // 64
constexpr size_t BOUTo  = 25696;    // 64
constexpr size_t BIHo   = 25760;    // 96
constexpr size_t BHHo   = 25856;    // 96
constexpr size_t BFCo   = 25952;    // 16 (1 used)
constexpr size_t INAo   = 25968;    // 1024
constexpr size_t OUTAo  = 26992;    // 1024
constexpr size_t CCNTo  = 28016;    // 1024 int (in-degree per node)
constexpr size_t DTFo   = 29040;    // 16 (dtype flag int)
constexpr size_t IEMo   = 29056;    // item_emb f32 32768
constexpr size_t REMo   = 61824;    // resp_emb f32 65536
constexpr size_t SUMEMBo= 127360;   // sum of item_emb over in-neighbors: 1024*32
constexpr size_t QCNTo  = 160128;   // [1024][16] ints: 16th-boundaries (rows < 64*(k+1))
constexpr size_t OMASKo = 176512;   // u64[1024][16]: omask[v] bit j = adj[v][j] (32768 f)
constexpr size_t CIDXo  = 209280;   // 1024*96 int (CSC col lists, ascending) = 98304
constexpr size_t BARo   = 307584;   // 64 counters, padded to 32-int (128B) stride = 2048
constexpr size_t PARTo  = 309632;   // partials f32 [par2][b64][CAPD][NSUB*32] — LAST
// sizes: 16-sub Pbuf = 4,194,304 f -> end 18.0 MB (proven to fit in R23);
//        8-sub = 2,097,152 -> 9.6 MB; 4-sub = 1,048,576 -> 5.4 MB.

// ---------------- helpers ----------------
__device__ __forceinline__ float bf2f(unsigned short u) {
    union { unsigned int i; float f; } x; x.i = ((unsigned int)u) << 16; return x.f;
}
__device__ __forceinline__ unsigned short f2bf(float f) {
    union { float f; unsigned int u; } x; x.f = f;
    unsigned int u = x.u;
    return (unsigned short)((u + 0x7fffu + ((u >> 16) & 1u)) >> 16);  // RNE
}
__device__ __forceinline__ float sigm(float x) { return 1.f / (1.f + __expf(-x)); }
__device__ __forceinline__ float tanhx(float x) {
    x = fminf(15.f, fmaxf(-15.f, x));
    float e = __expf(2.f * x);
    return (e - 1.f) / (e + 1.f);
}
__device__ __forceinline__ float ldg_any(const void* p, int i, int isbf) {
    return isbf ? bf2f(((const unsigned short*)p)[i]) : ((const float*)p)[i];
}

// Coherent-point (sc-flagged) 4B accessors (proven R13/R19).
__device__ __forceinline__ void cstore(float* p, float v) {
    __hip_atomic_store((unsigned int*)p, __float_as_uint(v),
                       __ATOMIC_RELAXED, __HIP_MEMORY_SCOPE_AGENT);
}
__device__ __forceinline__ float cload(const float* p) {
    return __uint_as_float(__hip_atomic_load((const unsigned int*)p,
                       __ATOMIC_RELAXED, __HIP_MEMORY_SCOPE_AGENT));
}

// NSUB-block per-batch epoch barrier (fence-free; payload is sc-coherent).
template<int NSUB>
__device__ __forceinline__ void barN(int* c, int& ep, int tid) {
    __syncthreads();
    if (tid == 0) {
        __hip_atomic_fetch_add(c, 1, __ATOMIC_RELAXED, __HIP_MEMORY_SCOPE_AGENT);
        const int target = NSUB * (++ep);
        while (__hip_atomic_load(c, __ATOMIC_RELAXED, __HIP_MEMORY_SCOPE_AGENT) < target)
            __builtin_amdgcn_s_sleep(1);
    } else {
        ++ep;
    }
    __syncthreads();
}

// ---------------- prep: zero dtype flag + barrier counters ----------------
__global__ void k_zero(float* __restrict__ ws)
{
    const int tg = threadIdx.x;
    if (tg == 0) ((int*)(ws + DTFo))[0] = 0;
    for (int i = tg; i < 2048; i += 256) ((int*)(ws + BARo))[i] = 0;
}

// ---------------- prep: detect input float dtype (multi-block) ----------------
__global__ void k_detect(const unsigned int* __restrict__ adjw, float* __restrict__ ws)
{
    const int tg  = blockIdx.x * blockDim.x + threadIdx.x;
    const int tot = gridDim.x * blockDim.x;
    int local = 0;
    for (int i = tg; i < 524288; i += tot) {
        unsigned int w = adjw[i];
        if ((w & 0xFFFFu) == 0x3F80u) local = 1;
    }
    if (__ballot(local) && (threadIdx.x & 63) == 0)
        atomicOr((int*)(ws + DTFo), 1);
}

// ---------------- prep: convert/pack weights -> f32 ----------------
__global__ void k_convert(const void* __restrict__ w_in,  const void* __restrict__ b_in,
                          const void* __restrict__ w_out, const void* __restrict__ b_out,
                          const void* __restrict__ in_a,  const void* __restrict__ out_a,
                          const void* __restrict__ w_ih,  const void* __restrict__ w_hh,
                          const void* __restrict__ b_ih,  const void* __restrict__ b_hh,
                          const void* __restrict__ w_fc,  const void* __restrict__ b_fc,
                          const void* __restrict__ item_emb, const void* __restrict__ resp_emb,
                          float* __restrict__ ws)
{
    const int isbf = ((const int*)(ws + DTFo))[0];
    const int tg  = blockIdx.x * blockDim.x + threadIdx.x;
    const int tot = gridDim.x * blockDim.x;
    for (int f = tg; f < 8192; f += tot) {
        int i = f & 63, j = f >> 6;
        ws[WINTo + f]  = ldg_any(w_in , i * 128 + j, isbf);
        ws[WOUTTo + f] = ldg_any(w_out, i * 128 + j, isbf);
    }
    for (int f = tg; f < 6144; f += tot) {
        int g = f % 96, j = f / 96;
        ws[WIHTo + f] = ldg_any(w_ih, g * 64 + j, isbf);
    }
    for (int f = tg; f < 3072; f += tot) ws[WHHo + f] = ldg_any(w_hh, f, isbf);
    for (int f = tg; f < 32;   f += tot) ws[WFCo + f] = ldg_any(w_fc, f, isbf);
    for (int f = tg; f < 64;   f += tot) { ws[BINo + f] = ldg_any(b_in, f, isbf); ws[BOUTo + f] = ldg_any(b_out, f, isbf); }
    for (int f = tg; f < 96;   f += tot) { ws[BIHo + f] = ldg_any(b_ih, f, isbf); ws[BHHo + f] = ldg_any(b_hh, f, isbf); }
    if (tg == 0) ws[BFCo] = ldg_any(b_fc, 0, isbf);
    for (int f = tg; f < 1024; f += tot) { ws[INAo + f] = ldg_any(in_a, f, isbf); ws[OUTAo + f] = ldg_any(out_a, f, isbf); }
    for (int f = tg; f < 32768; f += tot) ws[IEMo + f] = ldg_any(item_emb, f, isbf);
    for (int f = tg; f < 65536; f += tot) ws[REMo + f] = ldg_any(resp_emb, f, isbf);
}

// ---------------- prep: build CSC adjacency + 16th boundaries ----------------
__global__ void k_csc(const void* __restrict__ adj, float* __restrict__ ws)
{
    const int isbf = ((const int*)(ws + DTFo))[0];
    const int v = blockIdx.x;
    const int lane = threadIdx.x;
    int* ccnt = (int*)(ws + CCNTo);
    int* cidx = (int*)(ws + CIDXo);
    int* qcb  = (int*)(ws + QCNTo);   // [1024][16]
    int cnt = 0;
    int bnd[15];
    for (int ch = 0; ch < 16; ++ch) {   // each ch covers rows [64ch, 64ch+64)
        int row = ch * 64 + lane;
        bool nz;
        if (isbf) nz = (((const unsigned short*)adj)[row * 1024 + v] != 0);
        else      nz = (((const float*)adj)[row * 1024 + v] != 0.f);
        unsigned long long m = __ballot(nz);
        int pos = cnt + __popcll(m & ((1ull << lane) - 1ull));
        if (nz && pos < CAP) cidx[v * CAP + pos] = row;
        cnt += __popcll(m);
        if (ch < 15) bnd[ch] = (cnt > CAP) ? CAP : cnt;   // #neighbors with row < 64*(ch+1)
    }
    if (lane == 0) {
        ccnt[v] = (cnt > CAP) ? CAP : cnt;
        #pragma unroll
        for (int o = 0; o < 15; ++o) qcb[v * 16 + o] = bnd[o];
        qcb[v * 16 + 15] = 0;
    }
}

// ---------------- prep: out-neighbor bitmasks + static embedding sums ----------------
__global__ void k_emb(const void* __restrict__ adj, float* __restrict__ ws)
{
    const int isbf = ((const int*)(ws + DTFo))[0];
    const int v = blockIdx.x;
    const int lane = threadIdx.x;
    unsigned long long* om = (unsigned long long*)(ws + OMASKo);
    for (int w = 0; w < 16; ++w) {
        int col = w * 64 + lane;
        bool nz;
        if (isbf) nz = (((const unsigned short*)adj)[v * 1024 + col] != 0);
        else      nz = (((const float*)adj)[v * 1024 + col] != 0.f);
        unsigned long long m = __ballot(nz);
        if (lane == 0) om[v * 16 + w] = m;
    }
    const int cnt = ((const int*)(ws + CCNTo))[v];
    const int* cl = (const int*)(ws + CIDXo) + v * CAP;
    float acc = 0.f;
    for (int k = 0; k < cnt; ++k) {
        int u = cl[k];
        if (lane < 32) acc += ws[IEMo + u * 32 + lane];
    }
    if (lane < 32) ws[SUMEMBo + v * 32 + lane] = acc;
}

// ---------------- main: NSUB blocks per batch, persistent, PLAIN launch ----------------
// Body is EXACTLY the proven R19 code (112 VGPR, no spill). WPE=2 for ALL variants:
// at 112 VGPR the hardware co-schedules 4 waves/SIMD for the 16-sub shape on its own;
// declaring more only pressures the allocator into the 64-reg step (R23 failure).
template<int NSUB, int NTHR>
__global__ __launch_bounds__(NTHR, 2) void gkt_main(
    const int* __restrict__ item_ids, const int* __restrict__ responses,
    float* ws, float* __restrict__ out)
{
    constexpr int OWN   = N_ / NSUB;    // 64 / 128 / 256
    constexpr int WAVES = NTHR / 64;    // 4 or 8
    constexpr int QSTEP = 16 / NSUB;    // boundary-table stride: 1 / 2 / 4
    constexpr int PSTR  = NSUB * 32;    // Pbuf row stride
    constexpr int RPG   = OWN / (WAVES * 2);  // GRU rows per lane-group: 8 / 16 / 16
    extern __shared__ float smem[];
    float* h_lds = smem;                                        // [OWN][32]
    unsigned short* gi16 = (unsigned short*)(smem + OWN * 32);  // [OWN][96] bf16
    float* fea_stage = smem + OWN * 32 + OWN * 48;              // [WAVES][128]
    int* dlist = (int*)(fea_stage + WAVES * 128);               // [64]
    float* out_stage = (float*)(dlist + 64);                    // [OWN]

    const int tid  = threadIdx.x;
    const int lane = tid & 63;
    const int wave = tid >> 6;
    const int bid  = blockIdx.x;
    const int sub  = bid >> 6;                            // 0..NSUB-1
    const int b    = ((bid & 63) + (sub << 3)) & 63;      // scrambled: co-resident
    const int base = sub * OWN;                           //   blocks = diff batches
    const int s    = lane & 31;
    const int gsel = (lane >> 5) & 1;

    int* barc = (int*)(ws + BARo) + b * 32;               // 128B-strided counters
    const float* __restrict__ winT  = ws + WINTo;
    const float* __restrict__ woutT = ws + WOUTTo;
    const float* __restrict__ wihT  = ws + WIHTo;
    const float* __restrict__ whh   = ws + WHHo;
    const float* __restrict__ bin_f = ws + BINo;
    const float* __restrict__ bout_f= ws + BOUTo;
    const float* __restrict__ bih_f = ws + BIHo;
    const float* __restrict__ bhh_f = ws + BHHo;
    const float* __restrict__ ina_f = ws + INAo;
    const float* __restrict__ outa_f= ws + OUTAo;
    const float* __restrict__ iem   = ws + IEMo;
    const float* __restrict__ rem   = ws + REMo;
    const float* __restrict__ semb  = ws + SUMEMBo;
    const int* __restrict__ ccnt = (const int*)(ws + CCNTo);
    const int* __restrict__ cidx = (const int*)(ws + CIDXo);
    const int* __restrict__ qcb  = (const int*)(ws + QCNTo);
    const unsigned long long* __restrict__ omk = (const unsigned long long*)(ws + OMASKo);

    // init LDS: h = 0, gi = b_ih (bf16)
    for (int i = tid; i < OWN * 32; i += NTHR) h_lds[i] = 0.f;
    for (int i = tid; i < OWN * 96; i += NTHR) gi16[i] = f2bf(bih_f[i % 96]);

    // register-stationary GRU recurrent weights for this lane's state index s
    float wr[32], wz[32], wn[32];
    #pragma unroll
    for (int j = 0; j < 32; ++j) {
        wr[j] = whh[s * 32 + j];
        wz[j] = whh[(32 + s) * 32 + j];
        wn[j] = whh[(64 + s) * 32 + j];
    }
    const float bhr = bhh_f[s], bhz = bhh_f[32 + s], bhn = bhh_f[64 + s];
    const float wfcs = ws[WFCo + s];
    const float bfc  = ws[BFCo];
    __syncthreads();

    int ep = 0;
    const int gid = wave * 2 + gsel;   // group id; owns rows [gid*RPG, gid*RPG+RPG)

    for (int t = 0; t < T_; ++t) {
        const int item = item_ids[b * T_ + t];
        const int resp = responses[b * T_ + t];
        const int ndst0 = ccnt[item];
        const int ndst  = (ndst0 > CAPD) ? CAPD : ndst0;   // data max ~61 < 64
        if (tid < ndst) dlist[tid] = cidx[item * CAP + tid];
        __syncthreads();
        const float remv = (lane >= 32) ? rem[resp * 32 + (lane - 32)] : 0.f;

        float* Pbuf = ws + PARTo + ((size_t)(t & 1) * 64 + b) * (CAPD * PSTR);  // [i][PSTR]

        // ---- phase P: partial h-sums over own OWN rows, for every dst i ----
        for (int i = wave; i < ndst; i += WAVES) {
            const int v = dlist[i];
            const int k0 = (sub == 0) ? 0 : qcb[v * 16 + sub * QSTEP - 1];
            const int k1 = (sub == NSUB - 1) ? ccnt[v] : qcb[v * 16 + (sub + 1) * QSTEP - 1];
            float acc = 0.f;
            for (int k = k0; k < k1; ++k) {
                const int ul = cidx[v * CAP + k] - base;
                if (lane < 32) acc += h_lds[ul * 32 + lane];
            }
            if (lane < 32) cstore(Pbuf + i * PSTR + sub * 32 + lane, acc);
        }
        barN<NSUB>(barc, ep, tid);   // publish partials (the ONLY cross-block sync/step)

        // ---- phase A': FC + gi for dst nodes in OWN range (exact R19 body) ----
        float* fstage = fea_stage + wave * 128;
        for (int i = wave; i < ndst; i += WAVES) {
            const int v = dlist[i];
            if ((v / OWN) != sub) continue;          // wave-uniform skip
            const int vl = v & (OWN - 1);
            float own, agg;
            if (lane < 32) {
                own = h_lds[vl * 32 + lane];
                const float* pp = Pbuf + i * PSTR;
                agg = 0.f;
                #pragma unroll
                for (int q = 0; q < NSUB; ++q) agg += cload(pp + q * 32 + lane);
            } else {
                const int j = lane - 32;
                own = (v == item) ? remv : iem[v * 32 + j];
                const bool hasitem = (omk[item * 16 + (v >> 6)] >> (v & 63)) & 1ull;
                agg = semb[v * 32 + j] + (hasitem ? (remv - iem[item * 32 + j]) : 0.f);
            }
            fstage[lane]      = own;
            fstage[64 + lane] = agg;
            float ain = 0.f, aout = 0.f;
            const float4* f4p = (const float4*)fstage;
            #pragma unroll 8
            for (int c = 0; c < 32; ++c) {
                const float4 f = f4p[c];
                ain  += f.x * winT [(4*c+0)*64 + lane] + f.y * winT [(4*c+1)*64 + lane]
                      + f.z * winT [(4*c+2)*64 + lane] + f.w * winT [(4*c+3)*64 + lane];
                aout += f.x * woutT[(4*c+0)*64 + lane] + f.y * woutT[(4*c+1)*64 + lane]
                      + f.z * woutT[(4*c+2)*64 + lane] + f.w * woutT[(4*c+3)*64 + lane];
            }
            ain  += bin_f[lane];
            aout += bout_f[lane];
            const float dstv = outa_f[v] * aout + ina_f[v] * ain;
            fstage[lane] = dstv;   // reuse stage (same-wave LDS order; proven)
            float g0 = bih_f[lane];
            float g1 = (lane < 32) ? bih_f[64 + lane] : 0.f;
            const float4* d4p = (const float4*)fstage;
            #pragma unroll 8
            for (int c = 0; c < 16; ++c) {
                const float4 dv = d4p[c];
                g0 += dv.x * wihT[(4*c+0)*96 + lane] + dv.y * wihT[(4*c+1)*96 + lane]
                    + dv.z * wihT[(4*c+2)*96 + lane] + dv.w * wihT[(4*c+3)*96 + lane];
                if (lane < 32) {
                    g1 += dv.x * wihT[(4*c+0)*96 + 64 + lane] + dv.y * wihT[(4*c+1)*96 + 64 + lane]
                        + dv.z * wihT[(4*c+2)*96 + 64 + lane] + dv.w * wihT[(4*c+3)*96 + 64 + lane];
                }
            }
            gi16[vl * 96 + lane] = f2bf(g0);
            if (lane < 32) gi16[vl * 96 + 64 + lane] = f2bf(g1);
        }
        __syncthreads();   // gi_lds visible to phase B

        // ---- phase B: GRU on own rows [gid*RPG, gid*RPG+RPG), all LDS ----
        {
            int nl = gid * RPG;
            unsigned short cS = gi16[nl * 96 + s], c32 = gi16[nl * 96 + 32 + s], c64 = gi16[nl * 96 + 64 + s];
            const float4* hrow = (const float4*)(h_lds + nl * 32);
            float4 ch[8];
            #pragma unroll
            for (int q = 0; q < 8; ++q) ch[q] = hrow[q];
            float h_own = h_lds[nl * 32 + s];

            for (int i = 0; i < RPG; ++i, ++nl) {
                unsigned short nS = 0, n32 = 0, n64 = 0;
                float4 nh[8];
                float nh_own = 0.f;
                if (i < RPG - 1) {
                    nS  = gi16[(nl + 1) * 96 + s];
                    n32 = gi16[(nl + 1) * 96 + 32 + s];
                    n64 = gi16[(nl + 1) * 96 + 64 + s];
                    const float4* hnx = (const float4*)(h_lds + (nl + 1) * 32);
                    #pragma unroll
                    for (int q = 0; q < 8; ++q) nh[q] = hnx[q];
                    nh_own = h_lds[(nl + 1) * 32 + s];
                }
                float ar = bhr, az = bhz, an = bhn;
                const float* hf = (const float*)ch;
                #pragma unroll
                for (int j = 0; j < 32; ++j) {
                    const float hv = hf[j];
                    ar += wr[j] * hv; az += wz[j] * hv; an += wn[j] * hv;
                }
                const float gir = bf2f(cS), giz = bf2f(c32), gin = bf2f(c64);
                const float rg = sigm(gir + ar);
                const float zg = sigm(giz + az);
                const float ng = tanhx(gin + rg * an);
                const float hv2 = (1.f - zg) * ng + zg * h_own;
                h_lds[nl * 32 + s] = hv2;
                float red = hv2 * wfcs;
                red += __shfl_xor(red, 16); red += __shfl_xor(red, 8);
                red += __shfl_xor(red, 4);  red += __shfl_xor(red, 2);
                red += __shfl_xor(red, 1);
                if (s == 0) out_stage[nl] = sigm(red + bfc);   // staged; flush below
                if (t == T_ - 1) {
                    const int n = base + nl;
                    __builtin_nontemporal_store(hv2,
                                out + OUT0 + (size_t)b * 32768 + (size_t)n * 32 + s);
                }
                cS = nS; c32 = n32; c64 = n64; h_own = nh_own;
                #pragma unroll
                for (int q = 0; q < 8; ++q) ch[q] = nh[q];
            }
        }
        __syncthreads();   // h_lds + out_stage complete (also guards next-step phase P)

        // coalesced out flush: one contiguous OWN*4B store per block-step
        if (tid < OWN)
            __builtin_nontemporal_store(out_stage[tid],
                out + (size_t)b * 65536 + (size_t)t * 1024 + base + tid);
    }
}

extern "C" void kernel_launch(void* const* d_in, const int* in_sizes, int n_in,
                              void* d_out, int out_size, void* d_ws, size_t ws_size,
                              hipStream_t stream)
{
    (void)in_sizes; (void)n_in; (void)out_size;
    const int* item_ids  = (const int*)d_in[0];
    const int* responses = (const int*)d_in[1];
    const void* adj      = d_in[2];
    const void* item_emb = d_in[3];
    const void* resp_emb = d_in[4];
    const void* w_in  = d_in[5];
    const void* b_in  = d_in[6];
    const void* w_out = d_in[7];
    const void* b_out = d_in[8];
    const void* in_a  = d_in[9];
    const void* out_a = d_in[10];
    const void* w_ih  = d_in[11];
    const void* w_hh  = d_in[12];
    const void* b_ih  = d_in[13];
    const void* b_hh  = d_in[14];
    const void* w_fc  = d_in[15];
    const void* b_fc  = d_in[16];
    float* ws = (float*)d_ws;
    float* out = (float*)d_out;

    // LDS bytes per variant: (OWN*80 + WAVES*128 + 64 + OWN) * 4
    constexpr int LDS16B = (64  * 80 + 4 * 128 + 64 + 64 ) * 4;  // 22,912 B (4+/CU by LDS)
    constexpr int LDS8B  = (128 * 80 + 4 * 128 + 64 + 128) * 4;  // 43,776 B (2/CU)
    constexpr int LDS4B  = (256 * 80 + 8 * 128 + 64 + 256) * 4;  // 87,296 B (1/CU)

    (void)hipFuncSetAttribute((const void*)&gkt_main<16, 256>,
                              hipFuncAttributeMaxDynamicSharedMemorySize, LDS16B);
    (void)hipFuncSetAttribute((const void*)&gkt_main<8, 256>,
                              hipFuncAttributeMaxDynamicSharedMemorySize, LDS8B);
    (void)hipFuncSetAttribute((const void*)&gkt_main<4, 512>,
                              hipFuncAttributeMaxDynamicSharedMemorySize, LDS4B);

    k_zero<<<dim3(1), dim3(256), 0, stream>>>(ws);
    k_detect<<<dim3(256), dim3(256), 0, stream>>>((const unsigned int*)adj, ws);
    k_convert<<<dim3(64), dim3(256), 0, stream>>>(w_in, b_in, w_out, b_out, in_a, out_a,
                                                  w_ih, w_hh, b_ih, b_hh, w_fc, b_fc,
                                                  item_emb, resp_emb, ws);
    k_csc<<<dim3(1024), dim3(64), 0, stream>>>(adj, ws);
    k_emb<<<dim3(1024), dim3(64), 0, stream>>>(adj, ws);

    // Variant selection: ws capacity AND queried co-residency (needs 4 blocks/CU
    // for the 16-sub shape; at VGPR~112 + 22.9KB LDS the query should return >=4).
    const size_t need16 = (PARTo + (size_t)2 * 64 * CAPD * 512 + 64) * 4;  // ~18.0 MB
    const size_t need8  = (PARTo + (size_t)2 * 64 * CAPD * 256 + 64) * 4;  //  ~9.6 MB
    int occ16 = 0, occ8 = 0;
    (void)hipOccupancyMaxActiveBlocksPerMultiprocessor(
        &occ16, (const void*)&gkt_main<16, 256>, 256, (size_t)LDS16B);
    (void)hipOccupancyMaxActiveBlocksPerMultiprocessor(
        &occ8, (const void*)&gkt_main<8, 256>, 256, (size_t)LDS8B);

    if (ws_size >= need16 && occ16 >= 4) {
        gkt_main<16, 256><<<dim3(1024), dim3(256), LDS16B, stream>>>(item_ids, responses, ws, out);
    } else if (ws_size >= need8 && occ8 >= 2) {
        gkt_main<8, 256><<<dim3(512), dim3(256), LDS8B, stream>>>(item_ids, responses, ws, out);
    } else {
        gkt_main<4, 512><<<dim3(256), dim3(512), LDS4B, stream>>>(item_ids, responses, ws, out);
    }
}

// Round 12
// 2491.092 us; speedup vs baseline: 1.0075x; 1.0075x over previous
//
#include <hip/hip_runtime.h>

// ---------------- problem constants ----------------
constexpr int N_ = 1024;   // ITEM_SIZE
constexpr int B_ = 64;     // BATCH
constexpr int T_ = 64;     // SEQ
constexpr int CAP = 96;    // cidx capacity per node (max in-degree ~61 incl self-loop)
constexpr int CAPD = 64;   // dst capacity per step (ndst = indeg(item) <= ~61)
constexpr size_t OUT0 = (size_t)B_ * T_ * N_;   // outs f32, then h [B][N][32] f32

// ROUND-25: the TLP experiment, attempt #4. R24's profile proved the occupancy QUERY
// reports from the waves-per-eu metadata, not actual resources ((256,2) kernel with
// 112 VGPR + 22.9KB LDS queried <4 blocks/CU; R23's (256,4) kernel queried 4) — the
// 16-sub variant never launched. This round: 8-sub x 512-THREAD blocks <8,512>.
// Grid/scramble/barrier/traffic are EXACTLY R19's proven 512-block shape; only
// threads/block doubles -> 16 waves/CU at the same 2 blocks/CU. Residency math:
// LDS 45.8KB x2 = 91.6KB <= 160KB (slack); VGPR 112 -> 4 waves/SIMD = exactly 2
// blocks of 8 waves. Selection bypasses the broken query: hipFuncGetAttributes
// numRegs must be in (0,128] (=> >=4 waves/SIMD), else fall back <8,256> / <4,512>.
// Tripwires: Workgroup_Size must read 512; VGPR ~112-116 with ~75MB FETCH (no spill).

// ---------------- workspace layout (float offsets; Pbuf LAST, variant-sized) ----------------
constexpr size_t WINTo  = 0;        // w_in^T  [j][i] 128*64 = 8192
constexpr size_t WOUTTo = 8192;     // w_out^T                 8192
constexpr size_t WIHTo  = 16384;    // w_ih^T  [j][g]  64*96 = 6144
constexpr size_t WHHo   = 22528;    // w_hh row-major          3072
constexpr size_t WFCo   = 25600;    // 32
constexpr size_t BINo   = 25632;    // 64
constexpr size_t BOUTo  = 25696;    // 64
constexpr size_t BIHo   = 25760;    // 96
constexpr size_t BHHo   = 25856;    // 96
constexpr size_t BFCo   = 25952;    // 16 (1 used)
constexpr size_t INAo   = 25968;    // 1024
constexpr size_t OUTAo  = 26992;    // 1024
constexpr size_t CCNTo  = 28016;    // 1024 int (in-degree per node)
constexpr size_t DTFo   = 29040;    // 16 (dtype flag int)
constexpr size_t IEMo   = 29056;    // item_emb f32 32768
constexpr size_t REMo   = 61824;    // resp_emb f32 65536
constexpr size_t SUMEMBo= 127360;   // sum of item_emb over in-neighbors: 1024*32
constexpr size_t QCNTo  = 160128;   // [1024][16] ints: 16th-boundaries (rows < 64*(k+1))
constexpr size_t OMASKo = 176512;   // u64[1024][16]: omask[v] bit j = adj[v][j] (32768 f)
constexpr size_t CIDXo  = 209280;   // 1024*96 int (CSC col lists, ascending) = 98304
constexpr size_t BARo   = 307584;   // 64 counters, padded to 32-int (128B) stride = 2048
constexpr size_t PARTo  = 309632;   // partials f32 [par2][b64][CAPD][NSUB*32] — LAST
// 8-sub Pbuf = 2,097,152 f -> end 9.6 MB (proven); 4-sub = 1,048,576 -> 5.4 MB.

// ---------------- helpers ----------------
__device__ __forceinline__ float bf2f(unsigned short u) {
    union { unsigned int i; float f; } x; x.i = ((unsigned int)u) << 16; return x.f;
}
__device__ __forceinline__ unsigned short f2bf(float f) {
    union { float f; unsigned int u; } x; x.f = f;
    unsigned int u = x.u;
    return (unsigned short)((u + 0x7fffu + ((u >> 16) & 1u)) >> 16);  // RNE
}
__device__ __forceinline__ float sigm(float x) { return 1.f / (1.f + __expf(-x)); }
__device__ __forceinline__ float tanhx(float x) {
    x = fminf(15.f, fmaxf(-15.f, x));
    float e = __expf(2.f * x);
    return (e - 1.f) / (e + 1.f);
}
__device__ __forceinline__ float ldg_any(const void* p, int i, int isbf) {
    return isbf ? bf2f(((const unsigned short*)p)[i]) : ((const float*)p)[i];
}

// Coherent-point (sc-flagged) 4B accessors (proven R13/R19).
__device__ __forceinline__ void cstore(float* p, float v) {
    __hip_atomic_store((unsigned int*)p, __float_as_uint(v),
                       __ATOMIC_RELAXED, __HIP_MEMORY_SCOPE_AGENT);
}
__device__ __forceinline__ float cload(const float* p) {
    return __uint_as_float(__hip_atomic_load((const unsigned int*)p,
                       __ATOMIC_RELAXED, __HIP_MEMORY_SCOPE_AGENT));
}

// NSUB-block per-batch epoch barrier (fence-free; payload is sc-coherent).
template<int NSUB>
__device__ __forceinline__ void barN(int* c, int& ep, int tid) {
    __syncthreads();
    if (tid == 0) {
        __hip_atomic_fetch_add(c, 1, __ATOMIC_RELAXED, __HIP_MEMORY_SCOPE_AGENT);
        const int target = NSUB * (++ep);
        while (__hip_atomic_load(c, __ATOMIC_RELAXED, __HIP_MEMORY_SCOPE_AGENT) < target)
            __builtin_amdgcn_s_sleep(1);
    } else {
        ++ep;
    }
    __syncthreads();
}

// ---------------- prep: zero dtype flag + barrier counters ----------------
__global__ void k_zero(float* __restrict__ ws)
{
    const int tg = threadIdx.x;
    if (tg == 0) ((int*)(ws + DTFo))[0] = 0;
    for (int i = tg; i < 2048; i += 256) ((int*)(ws + BARo))[i] = 0;
}

// ---------------- prep: detect input float dtype (multi-block) ----------------
__global__ void k_detect(const unsigned int* __restrict__ adjw, float* __restrict__ ws)
{
    const int tg  = blockIdx.x * blockDim.x + threadIdx.x;
    const int tot = gridDim.x * blockDim.x;
    int local = 0;
    for (int i = tg; i < 524288; i += tot) {
        unsigned int w = adjw[i];
        if ((w & 0xFFFFu) == 0x3F80u) local = 1;
    }
    if (__ballot(local) && (threadIdx.x & 63) == 0)
        atomicOr((int*)(ws + DTFo), 1);
}

// ---------------- prep: convert/pack weights -> f32 ----------------
__global__ void k_convert(const void* __restrict__ w_in,  const void* __restrict__ b_in,
                          const void* __restrict__ w_out, const void* __restrict__ b_out,
                          const void* __restrict__ in_a,  const void* __restrict__ out_a,
                          const void* __restrict__ w_ih,  const void* __restrict__ w_hh,
                          const void* __restrict__ b_ih,  const void* __restrict__ b_hh,
                          const void* __restrict__ w_fc,  const void* __restrict__ b_fc,
                          const void* __restrict__ item_emb, const void* __restrict__ resp_emb,
                          float* __restrict__ ws)
{
    const int isbf = ((const int*)(ws + DTFo))[0];
    const int tg  = blockIdx.x * blockDim.x + threadIdx.x;
    const int tot = gridDim.x * blockDim.x;
    for (int f = tg; f < 8192; f += tot) {
        int i = f & 63, j = f >> 6;
        ws[WINTo + f]  = ldg_any(w_in , i * 128 + j, isbf);
        ws[WOUTTo + f] = ldg_any(w_out, i * 128 + j, isbf);
    }
    for (int f = tg; f < 6144; f += tot) {
        int g = f % 96, j = f / 96;
        ws[WIHTo + f] = ldg_any(w_ih, g * 64 + j, isbf);
    }
    for (int f = tg; f < 3072; f += tot) ws[WHHo + f] = ldg_any(w_hh, f, isbf);
    for (int f = tg; f < 32;   f += tot) ws[WFCo + f] = ldg_any(w_fc, f, isbf);
    for (int f = tg; f < 64;   f += tot) { ws[BINo + f] = ldg_any(b_in, f, isbf); ws[BOUTo + f] = ldg_any(b_out, f, isbf); }
    for (int f = tg; f < 96;   f += tot) { ws[BIHo + f] = ldg_any(b_ih, f, isbf); ws[BHHo + f] = ldg_any(b_hh, f, isbf); }
    if (tg == 0) ws[BFCo] = ldg_any(b_fc, 0, isbf);
    for (int f = tg; f < 1024; f += tot) { ws[INAo + f] = ldg_any(in_a, f, isbf); ws[OUTAo + f] = ldg_any(out_a, f, isbf); }
    for (int f = tg; f < 32768; f += tot) ws[IEMo + f] = ldg_any(item_emb, f, isbf);
    for (int f = tg; f < 65536; f += tot) ws[REMo + f] = ldg_any(resp_emb, f, isbf);
}

// ---------------- prep: build CSC adjacency + 16th boundaries ----------------
__global__ void k_csc(const void* __restrict__ adj, float* __restrict__ ws)
{
    const int isbf = ((const int*)(ws + DTFo))[0];
    const int v = blockIdx.x;
    const int lane = threadIdx.x;
    int* ccnt = (int*)(ws + CCNTo);
    int* cidx = (int*)(ws + CIDXo);
    int* qcb  = (int*)(ws + QCNTo);   // [1024][16]
    int cnt = 0;
    int bnd[15];
    for (int ch = 0; ch < 16; ++ch) {   // each ch covers rows [64ch, 64ch+64)
        int row = ch * 64 + lane;
        bool nz;
        if (isbf) nz = (((const unsigned short*)adj)[row * 1024 + v] != 0);
        else      nz = (((const float*)adj)[row * 1024 + v] != 0.f);
        unsigned long long m = __ballot(nz);
        int pos = cnt + __popcll(m & ((1ull << lane) - 1ull));
        if (nz && pos < CAP) cidx[v * CAP + pos] = row;
        cnt += __popcll(m);
        if (ch < 15) bnd[ch] = (cnt > CAP) ? CAP : cnt;   // #neighbors with row < 64*(ch+1)
    }
    if (lane == 0) {
        ccnt[v] = (cnt > CAP) ? CAP : cnt;
        #pragma unroll
        for (int o = 0; o < 15; ++o) qcb[v * 16 + o] = bnd[o];
        qcb[v * 16 + 15] = 0;
    }
}

// ---------------- prep: out-neighbor bitmasks + static embedding sums ----------------
__global__ void k_emb(const void* __restrict__ adj, float* __restrict__ ws)
{
    const int isbf = ((const int*)(ws + DTFo))[0];
    const int v = blockIdx.x;
    const int lane = threadIdx.x;
    unsigned long long* om = (unsigned long long*)(ws + OMASKo);
    for (int w = 0; w < 16; ++w) {
        int col = w * 64 + lane;
        bool nz;
        if (isbf) nz = (((const unsigned short*)adj)[v * 1024 + col] != 0);
        else      nz = (((const float*)adj)[v * 1024 + col] != 0.f);
        unsigned long long m = __ballot(nz);
        if (lane == 0) om[v * 16 + w] = m;
    }
    const int cnt = ((const int*)(ws + CCNTo))[v];
    const int* cl = (const int*)(ws + CIDXo) + v * CAP;
    float acc = 0.f;
    for (int k = 0; k < cnt; ++k) {
        int u = cl[k];
        if (lane < 32) acc += ws[IEMo + u * 32 + lane];
    }
    if (lane < 32) ws[SUMEMBo + v * 32 + lane] = acc;
}

// ---------------- main: NSUB blocks per batch, persistent, PLAIN launch ----------------
// Body is EXACTLY the proven R19 code (112 VGPR, no spill). WPE=2 for all variants.
template<int NSUB, int NTHR>
__global__ __launch_bounds__(NTHR, 2) void gkt_main(
    const int* __restrict__ item_ids, const int* __restrict__ responses,
    float* ws, float* __restrict__ out)
{
    constexpr int OWN   = N_ / NSUB;    // 128 / 256
    constexpr int WAVES = NTHR / 64;    // 4 or 8
    constexpr int QSTEP = 16 / NSUB;    // boundary-table stride: 2 / 4
    constexpr int PSTR  = NSUB * 32;    // Pbuf row stride
    constexpr int RPG   = OWN / (WAVES * 2);  // GRU rows per lane-group: 8 / 16
    extern __shared__ float smem[];
    float* h_lds = smem;                                        // [OWN][32]
    unsigned short* gi16 = (unsigned short*)(smem + OWN * 32);  // [OWN][96] bf16
    float* fea_stage = smem + OWN * 32 + OWN * 48;              // [WAVES][128]
    int* dlist = (int*)(fea_stage + WAVES * 128);               // [64]
    float* out_stage = (float*)(dlist + 64);                    // [OWN]

    const int tid  = threadIdx.x;
    const int lane = tid & 63;
    const int wave = tid >> 6;
    const int bid  = blockIdx.x;
    const int sub  = bid >> 6;                            // 0..NSUB-1
    const int b    = ((bid & 63) + (sub << 3)) & 63;      // scrambled: co-resident
    const int base = sub * OWN;                           //   blocks = diff batches
    const int s    = lane & 31;
    const int gsel = (lane >> 5) & 1;

    int* barc = (int*)(ws + BARo) + b * 32;               // 128B-strided counters
    const float* __restrict__ winT  = ws + WINTo;
    const float* __restrict__ woutT = ws + WOUTTo;
    const float* __restrict__ wihT  = ws + WIHTo;
    const float* __restrict__ whh   = ws + WHHo;
    const float* __restrict__ bin_f = ws + BINo;
    const float* __restrict__ bout_f= ws + BOUTo;
    const float* __restrict__ bih_f = ws + BIHo;
    const float* __restrict__ bhh_f = ws + BHHo;
    const float* __restrict__ ina_f = ws + INAo;
    const float* __restrict__ outa_f= ws + OUTAo;
    const float* __restrict__ iem   = ws + IEMo;
    const float* __restrict__ rem   = ws + REMo;
    const float* __restrict__ semb  = ws + SUMEMBo;
    const int* __restrict__ ccnt = (const int*)(ws + CCNTo);
    const int* __restrict__ cidx = (const int*)(ws + CIDXo);
    const int* __restrict__ qcb  = (const int*)(ws + QCNTo);
    const unsigned long long* __restrict__ omk = (const unsigned long long*)(ws + OMASKo);

    // init LDS: h = 0, gi = b_ih (bf16)
    for (int i = tid; i < OWN * 32; i += NTHR) h_lds[i] = 0.f;
    for (int i = tid; i < OWN * 96; i += NTHR) gi16[i] = f2bf(bih_f[i % 96]);

    // register-stationary GRU recurrent weights for this lane's state index s
    float wr[32], wz[32], wn[32];
    #pragma unroll
    for (int j = 0; j < 32; ++j) {
        wr[j] = whh[s * 32 + j];
        wz[j] = whh[(32 + s) * 32 + j];
        wn[j] = whh[(64 + s) * 32 + j];
    }
    const float bhr = bhh_f[s], bhz = bhh_f[32 + s], bhn = bhh_f[64 + s];
    const float wfcs = ws[WFCo + s];
    const float bfc  = ws[BFCo];
    __syncthreads();

    int ep = 0;
    const int gid = wave * 2 + gsel;   // group id; owns rows [gid*RPG, gid*RPG+RPG)

    for (int t = 0; t < T_; ++t) {
        const int item = item_ids[b * T_ + t];
        const int resp = responses[b * T_ + t];
        const int ndst0 = ccnt[item];
        const int ndst  = (ndst0 > CAPD) ? CAPD : ndst0;   // data max ~61 < 64
        if (tid < ndst) dlist[tid] = cidx[item * CAP + tid];
        __syncthreads();
        const float remv = (lane >= 32) ? rem[resp * 32 + (lane - 32)] : 0.f;

        float* Pbuf = ws + PARTo + ((size_t)(t & 1) * 64 + b) * (CAPD * PSTR);  // [i][PSTR]

        // ---- phase P: partial h-sums over own OWN rows, for every dst i ----
        for (int i = wave; i < ndst; i += WAVES) {
            const int v = dlist[i];
            const int k0 = (sub == 0) ? 0 : qcb[v * 16 + sub * QSTEP - 1];
            const int k1 = (sub == NSUB - 1) ? ccnt[v] : qcb[v * 16 + (sub + 1) * QSTEP - 1];
            float acc = 0.f;
            for (int k = k0; k < k1; ++k) {
                const int ul = cidx[v * CAP + k] - base;
                if (lane < 32) acc += h_lds[ul * 32 + lane];
            }
            if (lane < 32) cstore(Pbuf + i * PSTR + sub * 32 + lane, acc);
        }
        barN<NSUB>(barc, ep, tid);   // publish partials (the ONLY cross-block sync/step)

        // ---- phase A': FC + gi for dst nodes in OWN range (exact R19 body) ----
        float* fstage = fea_stage + wave * 128;
        for (int i = wave; i < ndst; i += WAVES) {
            const int v = dlist[i];
            if ((v / OWN) != sub) continue;          // wave-uniform skip
            const int vl = v & (OWN - 1);
            float own, agg;
            if (lane < 32) {
                own = h_lds[vl * 32 + lane];
                const float* pp = Pbuf + i * PSTR;
                agg = 0.f;
                #pragma unroll
                for (int q = 0; q < NSUB; ++q) agg += cload(pp + q * 32 + lane);
            } else {
                const int j = lane - 32;
                own = (v == item) ? remv : iem[v * 32 + j];
                const bool hasitem = (omk[item * 16 + (v >> 6)] >> (v & 63)) & 1ull;
                agg = semb[v * 32 + j] + (hasitem ? (remv - iem[item * 32 + j]) : 0.f);
            }
            fstage[lane]      = own;
            fstage[64 + lane] = agg;
            float ain = 0.f, aout = 0.f;
            const float4* f4p = (const float4*)fstage;
            #pragma unroll 8
            for (int c = 0; c < 32; ++c) {
                const float4 f = f4p[c];
                ain  += f.x * winT [(4*c+0)*64 + lane] + f.y * winT [(4*c+1)*64 + lane]
                      + f.z * winT [(4*c+2)*64 + lane] + f.w * winT [(4*c+3)*64 + lane];
                aout += f.x * woutT[(4*c+0)*64 + lane] + f.y * woutT[(4*c+1)*64 + lane]
                      + f.z * woutT[(4*c+2)*64 + lane] + f.w * woutT[(4*c+3)*64 + lane];
            }
            ain  += bin_f[lane];
            aout += bout_f[lane];
            const float dstv = outa_f[v] * aout + ina_f[v] * ain;
            fstage[lane] = dstv;   // reuse stage (same-wave LDS order; proven)
            float g0 = bih_f[lane];
            float g1 = (lane < 32) ? bih_f[64 + lane] : 0.f;
            const float4* d4p = (const float4*)fstage;
            #pragma unroll 8
            for (int c = 0; c < 16; ++c) {
                const float4 dv = d4p[c];
                g0 += dv.x * wihT[(4*c+0)*96 + lane] + dv.y * wihT[(4*c+1)*96 + lane]
                    + dv.z * wihT[(4*c+2)*96 + lane] + dv.w * wihT[(4*c+3)*96 + lane];
                if (lane < 32) {
                    g1 += dv.x * wihT[(4*c+0)*96 + 64 + lane] + dv.y * wihT[(4*c+1)*96 + 64 + lane]
                        + dv.z * wihT[(4*c+2)*96 + 64 + lane] + dv.w * wihT[(4*c+3)*96 + 64 + lane];
                }
            }
            gi16[vl * 96 + lane] = f2bf(g0);
            if (lane < 32) gi16[vl * 96 + 64 + lane] = f2bf(g1);
        }
        __syncthreads();   // gi_lds visible to phase B

        // ---- phase B: GRU on own rows [gid*RPG, gid*RPG+RPG), all LDS ----
        {
            int nl = gid * RPG;
            unsigned short cS = gi16[nl * 96 + s], c32 = gi16[nl * 96 + 32 + s], c64 = gi16[nl * 96 + 64 + s];
            const float4* hrow = (const float4*)(h_lds + nl * 32);
            float4 ch[8];
            #pragma unroll
            for (int q = 0; q < 8; ++q) ch[q] = hrow[q];
            float h_own = h_lds[nl * 32 + s];

            for (int i = 0; i < RPG; ++i, ++nl) {
                unsigned short nS = 0, n32 = 0, n64 = 0;
                float4 nh[8];
                float nh_own = 0.f;
                if (i < RPG - 1) {
                    nS  = gi16[(nl + 1) * 96 + s];
                    n32 = gi16[(nl + 1) * 96 + 32 + s];
                    n64 = gi16[(nl + 1) * 96 + 64 + s];
                    const float4* hnx = (const float4*)(h_lds + (nl + 1) * 32);
                    #pragma unroll
                    for (int q = 0; q < 8; ++q) nh[q] = hnx[q];
                    nh_own = h_lds[(nl + 1) * 32 + s];
                }
                float ar = bhr, az = bhz, an = bhn;
                const float* hf = (const float*)ch;
                #pragma unroll
                for (int j = 0; j < 32; ++j) {
                    const float hv = hf[j];
                    ar += wr[j] * hv; az += wz[j] * hv; an += wn[j] * hv;
                }
                const float gir = bf2f(cS), giz = bf2f(c32), gin = bf2f(c64);
                const float rg = sigm(gir + ar);
                const float zg = sigm(giz + az);
                const float ng = tanhx(gin + rg * an);
                const float hv2 = (1.f - zg) * ng + zg * h_own;
                h_lds[nl * 32 + s] = hv2;
                float red = hv2 * wfcs;
                red += __shfl_xor(red, 16); red += __shfl_xor(red, 8);
                red += __shfl_xor(red, 4);  red += __shfl_xor(red, 2);
                red += __shfl_xor(red, 1);
                if (s == 0) out_stage[nl] = sigm(red + bfc);   // staged; flush below
                if (t == T_ - 1) {
                    const int n = base + nl;
                    __builtin_nontemporal_store(hv2,
                                out + OUT0 + (size_t)b * 32768 + (size_t)n * 32 + s);
                }
                cS = nS; c32 = n32; c64 = n64; h_own = nh_own;
                #pragma unroll
                for (int q = 0; q < 8; ++q) ch[q] = nh[q];
            }
        }
        __syncthreads();   // h_lds + out_stage complete (also guards next-step phase P)

        // coalesced out flush: one contiguous OWN*4B store per block-step
        if (tid < OWN)
            __builtin_nontemporal_store(out_stage[tid],
                out + (size_t)b * 65536 + (size_t)t * 1024 + base + tid);
    }
}

extern "C" void kernel_launch(void* const* d_in, const int* in_sizes, int n_in,
                              void* d_out, int out_size, void* d_ws, size_t ws_size,
                              hipStream_t stream)
{
    (void)in_sizes; (void)n_in; (void)out_size;
    const int* item_ids  = (const int*)d_in[0];
    const int* responses = (const int*)d_in[1];
    const void* adj      = d_in[2];
    const void* item_emb = d_in[3];
    const void* resp_emb = d_in[4];
    const void* w_in  = d_in[5];
    const void* b_in  = d_in[6];
    const void* w_out = d_in[7];
    const void* b_out = d_in[8];
    const void* in_a  = d_in[9];
    const void* out_a = d_in[10];
    const void* w_ih  = d_in[11];
    const void* w_hh  = d_in[12];
    const void* b_ih  = d_in[13];
    const void* b_hh  = d_in[14];
    const void* w_fc  = d_in[15];
    const void* b_fc  = d_in[16];
    float* ws = (float*)d_ws;
    float* out = (float*)d_out;

    // LDS bytes per variant: (OWN*80 + WAVES*128 + 64 + OWN) * 4
    constexpr int LDS8W8 = (128 * 80 + 8 * 128 + 64 + 128) * 4;  // 45,824 B (8-sub, 512thr)
    constexpr int LDS8B  = (128 * 80 + 4 * 128 + 64 + 128) * 4;  // 43,776 B (8-sub, 256thr)
    constexpr int LDS4B  = (256 * 80 + 8 * 128 + 64 + 256) * 4;  // 87,296 B (4-sub, 512thr)

    (void)hipFuncSetAttribute((const void*)&gkt_main<8, 512>,
                              hipFuncAttributeMaxDynamicSharedMemorySize, LDS8W8);
    (void)hipFuncSetAttribute((const void*)&gkt_main<8, 256>,
                              hipFuncAttributeMaxDynamicSharedMemorySize, LDS8B);
    (void)hipFuncSetAttribute((const void*)&gkt_main<4, 512>,
                              hipFuncAttributeMaxDynamicSharedMemorySize, LDS4B);

    k_zero<<<dim3(1), dim3(256), 0, stream>>>(ws);
    k_detect<<<dim3(256), dim3(256), 0, stream>>>((const unsigned int*)adj, ws);
    k_convert<<<dim3(64), dim3(256), 0, stream>>>(w_in, b_in, w_out, b_out, in_a, out_a,
                                                  w_ih, w_hh, b_ih, b_hh, w_fc, b_fc,
                                                  item_emb, resp_emb, ws);
    k_csc<<<dim3(1024), dim3(64), 0, stream>>>(adj, ws);
    k_emb<<<dim3(1024), dim3(64), 0, stream>>>(adj, ws);

    // ---- variant selection ----
    // The hipOccupancy query reports from the kernel's waves-per-eu metadata (R23/R24
    // evidence), so compute residency from ACTUAL resources instead:
    //   blocks/CU by VGPR = (4 SIMDs * floor(512/vgpr) waves) / (NTHR/64 waves per block)
    //   blocks/CU by LDS  = 163840 / LDS_bytes
    // <8,512> needs 2 blocks/CU: vgpr <= 128 (=> 4 waves/SIMD -> 16 waves -> 2 blocks)
    // and LDS 45.8KB*2 <= 160KB (always true). Spill regime (vgpr > 128) -> fallback.
    const size_t need8 = (PARTo + (size_t)2 * 64 * CAPD * 256 + 64) * 4;  // ~9.6 MB

    hipFuncAttributes fa{};
    bool big_ok = false;
    if (hipFuncGetAttributes(&fa, (const void*)&gkt_main<8, 512>) == hipSuccess) {
        const int vgpr = fa.numRegs;
        if (vgpr > 0 && vgpr <= 128) {
            const int waves_per_simd = 512 / vgpr;             // >= 4
            const int blocks_by_vgpr = (waves_per_simd * 4) / 8;  // 8 waves/block
            const int blocks_by_lds  = 163840 / LDS8W8;           // 3
            big_ok = (blocks_by_vgpr >= 2) && (blocks_by_lds >= 2);
        }
    }

    if (big_ok && ws_size >= need8) {
        gkt_main<8, 512><<<dim3(512), dim3(512), LDS8W8, stream>>>(item_ids, responses, ws, out);
    } else {
        int occ8 = 0;
        (void)hipOccupancyMaxActiveBlocksPerMultiprocessor(
            &occ8, (const void*)&gkt_main<8, 256>, 256, (size_t)LDS8B);
        if (ws_size >= need8 && occ8 >= 2) {
            gkt_main<8, 256><<<dim3(512), dim3(256), LDS8B, stream>>>(item_ids, responses, ws, out);
        } else {
            gkt_main<4, 512><<<dim3(256), dim3(512), LDS4B, stream>>>(item_ids, responses, ws, out);
        }
    }
}